// Round 7
// baseline (322.369 us; speedup 1.0000x reference)
//
#include <hip/hip_runtime.h>
#include <hip/hip_bf16.h>

#define NB 16
#define NN 1024
#define NP 1025
#define ND 24
#define N_ITERS 20
#define PSTR 1040                         // padded potential stride (16B aligned)

#define LOG2E  1.4426950408889634f
#define LN2    0.6931471805599453f
#define MNORM  7.6246189861593985f        // -norm = log(2048)
#define NORM_C (-7.6246189861593985f)
#define LOGN_C ( 6.9314718055994531f)
#define MU_LIN 4.8828125e-4f              // 2^-11
#define SC2    0.29448976969431680f       // log2e / sqrt(24)
#define SCN    0.20412414523193154f       // 1 / sqrt(24)

// ---- ws layout (fast path): fp8 t = 2^(c*log2e), [b][i<1024][j<1024]
#define T_BYTES  ((size_t)NB * NN * NN)   // 16 MiB
#define PU_OFF   T_BYTES
#define PV_OFF   (PU_OFF + (size_t)NB * PSTR * 4)
#define WS_NEEDED (PV_OFF + (size_t)NB * PSTR * 4)

typedef float f32x2 __attribute__((ext_vector_type(2)));

#if defined(__has_builtin)
# if __has_builtin(__builtin_amdgcn_cvt_pk_f32_fp8) && __has_builtin(__builtin_amdgcn_cvt_pk_fp8_f32)
#  define HW_FP8 1
# endif
#endif

__device__ __forceinline__ float e2(float x){ return __builtin_amdgcn_exp2f(x); }

#ifdef HW_FP8
template <bool HI>
__device__ __forceinline__ f32x2 dec2(unsigned v){
  auto r = __builtin_amdgcn_cvt_pk_f32_fp8((int)v, HI);
  f32x2 o; o.x = r[0]; o.y = r[1]; return o;
}
__device__ __forceinline__ unsigned enc4(float a, float b, float c, float d){
  int lo = __builtin_amdgcn_cvt_pk_fp8_f32(a, b, 0, false);
  return (unsigned)__builtin_amdgcn_cvt_pk_fp8_f32(c, d, lo, true);
}
#else
__device__ __forceinline__ float dec1(unsigned x){
  unsigned e = (x >> 3) & 15, m = x & 7;
  float v = e ? ldexpf(1.f + m * 0.125f, (int)e - 7) : ldexpf(m * 0.125f, -6);
  return (x & 0x80) ? -v : v;
}
template <bool HI>
__device__ __forceinline__ f32x2 dec2(unsigned v){
  unsigned sh = HI ? 16 : 0;
  f32x2 o; o.x = dec1((v >> sh) & 0xff); o.y = dec1((v >> (sh + 8)) & 0xff); return o;
}
__device__ __forceinline__ unsigned enc1(float f){
  f = fminf(fmaxf(f, 0.f), 448.f);
  if (!(f > 0.f)) return 0u;
  unsigned bits = __float_as_uint(f);
  int e = (int)((bits >> 23) & 255) - 127 + 7;
  if (e >= 1) {
    unsigned m = bits & 0x7fffff;
    unsigned man3 = (m + 0x7ffff + ((m >> 20) & 1)) >> 20;
    if (man3 & 8) { man3 = 0; e += 1; }
    if (e > 15) { e = 15; man3 = 6; }
    if (e == 15 && man3 == 7) man3 = 6;            // avoid NaN encoding
    return (unsigned)((e << 3) | man3);
  }
  float q = f * 512.f;                              // units of 2^-9
  unsigned k = (unsigned)(q + 0.5f); if (k > 7) k = 7;
  return k;
}
__device__ __forceinline__ unsigned enc4(float a, float b, float c, float d){
  return enc1(a) | (enc1(b) << 8) | (enc1(c) << 16) | (enc1(d) << 24);
}
#endif

// ---------------------------------------------------------------------------
// t[b][i][j] = fp8( 2^( (dsc0_i . dsc1_j) * log2e/sqrt(24) ) ), i,j < 1024
// ---------------------------------------------------------------------------
__global__ __launch_bounds__(256) void scores_k(
    const float* __restrict__ d0, const float* __restrict__ d1,
    unsigned* __restrict__ t)
{
  __shared__ float As[ND][64];
  __shared__ float Bs[ND][64];
  const int b  = blockIdx.z;
  const int i0 = blockIdx.y * 64;
  const int j0 = blockIdx.x * 64;
  const int tid = threadIdx.x;
  const float* pa = d0 + b * ND * NN;
  const float* pb = d1 + b * ND * NN;
  for (int e = tid; e < ND * 64; e += 256) {
    int dd = e >> 6, cc = e & 63;
    As[dd][cc] = pa[dd * NN + i0 + cc];
    Bs[dd][cc] = pb[dd * NN + j0 + cc];
  }
  __syncthreads();
  const int tx = tid & 15, ty = tid >> 4;
  float acc[4][4] = {};
  #pragma unroll
  for (int dd = 0; dd < ND; ++dd) {
    float a[4], bb[4];
    #pragma unroll
    for (int r = 0; r < 4; ++r) a[r]  = As[dd][ty * 4 + r];
    #pragma unroll
    for (int c = 0; c < 4; ++c) bb[c] = Bs[dd][tx * 4 + c];
    #pragma unroll
    for (int r = 0; r < 4; ++r)
      #pragma unroll
      for (int c = 0; c < 4; ++c)
        acc[r][c] = fmaf(a[r], bb[c], acc[r][c]);
  }
  #pragma unroll
  for (int r = 0; r < 4; ++r) {
    size_t base = ((size_t)b * NN + (i0 + ty * 4 + r)) * NN + j0 + tx * 4;
    float t0 = fminf(e2(acc[r][0] * SC2), 448.f);
    float t1 = fminf(e2(acc[r][1] * SC2), 448.f);
    float t2 = fminf(e2(acc[r][2] * SC2), 448.f);
    float t3 = fminf(e2(acc[r][3] * SC2), 448.f);
    t[base >> 2] = enc4(t0, t1, t2, t3);
  }
}

// pv = 1 everywhere (first row pass sees v = 0)
__global__ __launch_bounds__(256) void init_k(float* __restrict__ pv)
{
  int idx = blockIdx.x * 256 + threadIdx.x;   // NB * PSTR = 16640
  pv[idx] = 1.f;
}

// ---------------------------------------------------------------------------
// row pass: pu[i] = mu_i / ( sum_j t_ij pv_j + ta * pv[1024] )
// grid 2064: b = bid&15 (XCD pin), rblk = bid>>4 (128 row-blocks + 1 dust)
// ---------------------------------------------------------------------------
__global__ __launch_bounds__(512) void row_k(
    const unsigned* __restrict__ t,
    const float* __restrict__ pv, const float* __restrict__ alpha_p,
    float* __restrict__ pu)
{
  const int bid = blockIdx.x;
  const int b = bid & 15;
  const int rblk = bid >> 4;
  const int w = threadIdx.x >> 6, lane = threadIdx.x & 63;
  const float* pvb = pv + b * PSTR;
  const float ta = e2((*alpha_p) * LOG2E);     // e^alpha
  if (rblk == 128) {                            // dustbin row: R = ta * sum(pv)
    if (w) return;
    float sd = 0.f;
    for (int k = lane; k < NP; k += 64) sd += pvb[k];
    #pragma unroll
    for (int off = 32; off; off >>= 1) sd += __shfl_xor(sd, off, 64);
    if (lane == 0) pu[b * PSTR + NN] = 0.5f / (ta * sd);
    return;
  }
  const int i = rblk * 8 + w;
  const unsigned* trow = t + ((((size_t)b * NN + i) * NN) >> 2) + lane * 4;
  uint4 q = *reinterpret_cast<const uint4*>(trow);
  const float4* pvv = reinterpret_cast<const float4*>(pvb + lane * 16);
  float4 p0 = pvv[0], p1 = pvv[1], p2 = pvv[2], p3 = pvv[3];
  f32x2 t0 = dec2<false>(q.x), t1 = dec2<true>(q.x);
  f32x2 t2 = dec2<false>(q.y), t3 = dec2<true>(q.y);
  f32x2 t4 = dec2<false>(q.z), t5 = dec2<true>(q.z);
  f32x2 t6 = dec2<false>(q.w), t7 = dec2<true>(q.w);
  float s = 0.f;
  s = fmaf(t0.x, p0.x, s); s = fmaf(t0.y, p0.y, s);
  s = fmaf(t1.x, p0.z, s); s = fmaf(t1.y, p0.w, s);
  s = fmaf(t2.x, p1.x, s); s = fmaf(t2.y, p1.y, s);
  s = fmaf(t3.x, p1.z, s); s = fmaf(t3.y, p1.w, s);
  s = fmaf(t4.x, p2.x, s); s = fmaf(t4.y, p2.y, s);
  s = fmaf(t5.x, p2.z, s); s = fmaf(t5.y, p2.w, s);
  s = fmaf(t6.x, p3.x, s); s = fmaf(t6.y, p3.y, s);
  s = fmaf(t7.x, p3.z, s); s = fmaf(t7.y, p3.w, s);
  #pragma unroll
  for (int off = 32; off; off >>= 1) s += __shfl_xor(s, off, 64);
  if (lane == 0)
    pu[b * PSTR + i] = MU_LIN / (s + ta * pvb[NN]);
}

// ---------------------------------------------------------------------------
// col pass: pv[j] = nu_j / ( sum_i t_ij pu_i + ta * pu[1024] )
// grid 128: b = bid&15, j0 = (bid>>4)*128; 16 waves x 64 rows; lane = 2 cols
// ---------------------------------------------------------------------------
__global__ __launch_bounds__(1024) void col_k(
    const unsigned char* __restrict__ t,
    const float* __restrict__ pu, const float* __restrict__ alpha_p,
    float* __restrict__ pv)
{
  __shared__ float Ul[NP];
  __shared__ float SS[16][128];
  const int bid = blockIdx.x;
  const int b = bid & 15;
  const int j0 = (bid >> 4) * 128;
  const int tid = threadIdx.x;
  const float* pub = pu + b * PSTR;
  for (int k = tid; k < NP; k += 1024) Ul[k] = pub[k];
  __syncthreads();
  const int w = tid >> 6, lane = tid & 63;
  const unsigned char* pc = t + (size_t)b * NN * NN + j0 + 2 * lane;
  const int i0 = w * 64;
  float s0 = 0.f, s1 = 0.f;
  #pragma unroll 8
  for (int ii = i0; ii < i0 + 64; ++ii) {
    unsigned h = *reinterpret_cast<const unsigned short*>(pc + (size_t)ii * NN);
    f32x2 tt = dec2<false>(h);
    float uv = Ul[ii];
    s0 = fmaf(tt.x, uv, s0);
    s1 = fmaf(tt.y, uv, s1);
  }
  SS[w][2 * lane]     = s0;
  SS[w][2 * lane + 1] = s1;
  __syncthreads();
  const float ta = e2((*alpha_p) * LOG2E);
  if (tid < 128) {
    float s = 0.f;
    #pragma unroll
    for (int r = 0; r < 16; ++r) s += SS[r][tid];
    s += ta * Ul[NN];                        // dustbin row contribution
    pv[b * PSTR + j0 + tid] = MU_LIN / s;
  } else if (j0 == 0 && w == 2) {            // dustbin col: S = ta * sum(pu)
    float sd = 0.f;
    for (int k = lane; k < NP; k += 64) sd += Ul[k];
    #pragma unroll
    for (int off = 32; off; off >>= 1) sd += __shfl_xor(sd, off, 64);
    if (lane == 0) pv[b * PSTR + NN] = 0.5f / (ta * sd);
  }
}

// ---------------------------------------------------------------------------
// final: Z = c_exact + (log2(pu_i) + log2(pv_j)) * ln2 + MNORM
// c recomputed exactly from descriptors (24-deep GEMM)
// ---------------------------------------------------------------------------
__global__ __launch_bounds__(512) void final_k(
    const float* __restrict__ d0, const float* __restrict__ d1,
    const float* __restrict__ pu, const float* __restrict__ pv,
    const float* __restrict__ alpha_p, float* __restrict__ Z)
{
  __shared__ float VL[NP];
  __shared__ float A8[ND][8];
  __shared__ float Bt[ND][128];
  const int bid = blockIdx.x;
  const int b = bid & 15;
  const int rblk = bid >> 4;
  const int tid = threadIdx.x;
  const int w = tid >> 6, lane = tid & 63;
  const float alpha = *alpha_p;
  for (int k = tid; k < NP; k += 512) VL[k] = __log2f(pv[b * PSTR + k]);
  const int i0 = rblk * 8;
  if (rblk < 128) {
    for (int e = tid; e < ND * 8; e += 512) {
      int dd = e >> 3, r = e & 7;
      A8[dd][r] = d0[b * ND * NN + dd * NN + i0 + r];
    }
  }
  __syncthreads();
  if (rblk == 128) {                           // dustbin row i = 1024
    if (w == 0) {
      float u24 = __log2f(pu[b * PSTR + NN]);
      float* zrow = Z + ((size_t)b * NP + NN) * NP;
      for (int j = lane; j < NP; j += 64)
        zrow[j] = fmaf(u24 + VL[j], LN2, alpha + MNORM);
    }
    return;
  }
  const int i = i0 + w;
  const float ui = __log2f(pu[b * PSTR + i]);
  float ar[ND];
  #pragma unroll
  for (int dd = 0; dd < ND; ++dd) ar[dd] = A8[dd][w];
  float* zrow = Z + ((size_t)b * NP + i) * NP;
  const float* pbb = d1 + b * ND * NN;
  for (int ct = 0; ct < 8; ++ct) {
    __syncthreads();
    for (int e = tid; e < ND * 128; e += 512) {
      int dd = e >> 7, cc = e & 127;
      Bt[dd][cc] = pbb[dd * NN + ct * 128 + cc];
    }
    __syncthreads();
    const int c0 = 2 * lane;
    float dot0 = 0.f, dot1 = 0.f;
    #pragma unroll
    for (int dd = 0; dd < ND; ++dd) {
      float2 bb = *reinterpret_cast<const float2*>(&Bt[dd][c0]);
      dot0 = fmaf(ar[dd], bb.x, dot0);
      dot1 = fmaf(ar[dd], bb.y, dot1);
    }
    const int j = ct * 128 + c0;
    float2 zz;
    zz.x = fmaf(dot0, SCN, fmaf(ui + VL[j],     LN2, MNORM));
    zz.y = fmaf(dot1, SCN, fmaf(ui + VL[j + 1], LN2, MNORM));
    *reinterpret_cast<float2*>(zrow + j) = zz;
  }
  if (lane == 0)
    zrow[NN] = fmaf(ui + VL[NN], LN2, alpha + MNORM);  // dustbin col
}

// ===========================================================================
// Fallback path (round-2 verified, f32 in d_out) if ws too small
// ===========================================================================
__global__ __launch_bounds__(256) void fb_scores(
    const float* __restrict__ d0, const float* __restrict__ d1, float* __restrict__ C)
{
  __shared__ float As[ND][64];
  __shared__ float Bs[ND][64];
  const int b  = blockIdx.z;
  const int n0 = blockIdx.y * 64;
  const int m0 = blockIdx.x * 64;
  const int tid = threadIdx.x;
  const float* pa = d0 + b * ND * NN;
  const float* pb = d1 + b * ND * NN;
  for (int e = tid; e < ND * 64; e += 256) {
    int dd = e >> 6, cc = e & 63;
    As[dd][cc] = pa[dd * NN + n0 + cc];
    Bs[dd][cc] = pb[dd * NN + m0 + cc];
  }
  __syncthreads();
  const int tx = tid & 15, ty = tid >> 4;
  float acc[4][4] = {};
  #pragma unroll
  for (int dd = 0; dd < ND; ++dd) {
    float a[4], bb[4];
    #pragma unroll
    for (int r = 0; r < 4; ++r) a[r]  = As[dd][ty * 4 + r];
    #pragma unroll
    for (int c = 0; c < 4; ++c) bb[c] = Bs[dd][tx * 4 + c];
    #pragma unroll
    for (int r = 0; r < 4; ++r)
      #pragma unroll
      for (int c = 0; c < 4; ++c)
        acc[r][c] = fmaf(a[r], bb[c], acc[r][c]);
  }
  const float sc = 0.20412414523193154f;
  #pragma unroll
  for (int r = 0; r < 4; ++r) {
    size_t base = ((size_t)b * NP + n0 + ty * 4 + r) * NP + m0 + tx * 4;
    #pragma unroll
    for (int c = 0; c < 4; ++c)
      C[base + c] = acc[r][c] * sc;
  }
}
__global__ __launch_bounds__(256) void fb_init(
    float* __restrict__ C, float* __restrict__ v, const float* __restrict__ alpha_p)
{
  const float alpha = *alpha_p;
  int idx = blockIdx.x * 256 + threadIdx.x;
  if (idx >= NB * NP) return;
  int b = idx / NP, x = idx - b * NP;
  C[((size_t)b * NP + NN) * NP + x] = alpha;
  C[((size_t)b * NP + x) * NP + NN] = alpha;
  v[idx] = 0.f;
}
__global__ __launch_bounds__(256) void fb_row(
    const float* __restrict__ C, const float* __restrict__ v, float* __restrict__ u)
{
  const int wid  = (blockIdx.x * 256 + threadIdx.x) >> 6;
  const int lane = threadIdx.x & 63;
  const int b = wid / NP, i = wid - b * NP;
  const float* crow = C + ((size_t)b * NP + i) * NP;
  const float* vb = v + b * NP;
  float s = 0.f;
  #pragma unroll
  for (int k = 0; k < 17; ++k) {
    int j = k * 64 + lane;
    if (j < NP) s += __expf(crow[j] + vb[j]);
  }
  #pragma unroll
  for (int off = 32; off; off >>= 1) s += __shfl_xor(s, off, 64);
  if (lane == 0) {
    float log_mu = NORM_C + (i == NN ? LOGN_C : 0.f);
    u[b * NP + i] = log_mu - __logf(s);
  }
}
__global__ __launch_bounds__(256) void fb_col(
    const float* __restrict__ C, const float* __restrict__ u, float* __restrict__ v)
{
  const int b  = blockIdx.y;
  const int tx = threadIdx.x & 31, ty = threadIdx.x >> 5;
  const int j  = blockIdx.x * 32 + tx;
  const bool valid = (j < NP);
  const float* cbp = C + (size_t)b * NP * NP;
  const float* ub = u + b * NP;
  float s = 0.f;
  if (valid) {
    #pragma unroll 4
    for (int i = ty; i < NP; i += 8)
      s += __expf(cbp[(size_t)i * NP + j] + ub[i]);
  }
  __shared__ float ss[8][32];
  ss[ty][tx] = s;
  __syncthreads();
  if (ty == 0 && valid) {
    #pragma unroll
    for (int r = 1; r < 8; ++r) s += ss[r][tx];
    float log_nu = NORM_C + (j == NN ? LOGN_C : 0.f);
    v[b * NP + j] = log_nu - __logf(s);
  }
}
__global__ __launch_bounds__(256) void fb_final(
    float* __restrict__ C, const float* __restrict__ u, const float* __restrict__ v)
{
  int idx = blockIdx.x * 256 + threadIdx.x;
  const int total = NB * NP * NP;
  if (idx >= total) return;
  int b = idx / (NP * NP);
  int rem = idx - b * (NP * NP);
  int i = rem / NP, j = rem - i * NP;
  C[idx] = C[idx] + u[b * NP + i] + v[b * NP + j] - NORM_C;
}

extern "C" void kernel_launch(void* const* d_in, const int* in_sizes, int n_in,
                              void* d_out, int out_size, void* d_ws, size_t ws_size,
                              hipStream_t stream) {
  const float* d0    = (const float*)d_in[0];
  const float* d1    = (const float*)d_in[1];
  const float* alpha = (const float*)d_in[2];
  float* Z = (float*)d_out;

  if (ws_size >= WS_NEEDED) {
    unsigned* t = (unsigned*)d_ws;
    float* pu = (float*)((char*)d_ws + PU_OFF);
    float* pv = (float*)((char*)d_ws + PV_OFF);

    scores_k<<<dim3(16, 16, NB), 256, 0, stream>>>(d0, d1, t);
    init_k<<<(NB * PSTR) / 256, 256, 0, stream>>>(pv);

    for (int it = 0; it < N_ITERS; ++it) {
      row_k<<<2064, 512, 0, stream>>>(t, pv, alpha, pu);
      col_k<<<128, 1024, 0, stream>>>((const unsigned char*)t, pu, alpha, pv);
    }
    final_k<<<2064, 512, 0, stream>>>(d0, d1, pu, pv, alpha, Z);
  } else {
    float* v = (float*)d_ws;
    float* u = v + NB * NP;
    fb_scores<<<dim3(NN / 64, NN / 64, NB), 256, 0, stream>>>(d0, d1, Z);
    fb_init<<<(NB * NP + 255) / 256, 256, 0, stream>>>(Z, v, alpha);
    for (int it = 0; it < N_ITERS; ++it) {
      fb_row<<<(NB * NP) / 4, 256, 0, stream>>>(Z, v, u);
      fb_col<<<dim3((NP + 31) / 32, NB), 256, 0, stream>>>(Z, u, v);
    }
    fb_final<<<(NB * NP * NP + 255) / 256, 256, 0, stream>>>(Z, u, v);
  }
}